// Round 14
// baseline (326.705 us; speedup 1.0000x reference)
//
#include <hip/hip_runtime.h>
#include <hip/hip_bf16.h>

typedef __attribute__((ext_vector_type(4))) float v4f;
typedef __attribute__((ext_vector_type(8))) short v8s;
typedef __attribute__((ext_vector_type(4))) unsigned v4u;
typedef __attribute__((ext_vector_type(2))) unsigned v2u;

// full RNE fp32->bf16 (prep kernel only)
__device__ __forceinline__ short f2bf(float f) {
  union { float f; unsigned u; } v; v.f = f;
  unsigned r = v.u + 0x7FFFu + ((v.u >> 16) & 1u);
  return (short)(r >> 16);
}
// packed 2xfp32 -> bf16x2, single v_cvt_pk_bf16_f32
__device__ __forceinline__ unsigned pk2(float a, float b) {
  union { __hip_bfloat162 h; unsigned u; } c;
  c.h = __float22bfloat162_rn(make_float2(a, b));
  return c.u;
}

// prep: pack W1 [128x256] + W2 [256x256] into bf16 MFMA A-fragment order
// (16x16x32: lane l of frag (mt,kt) holds A'[n=mt*16+(l&15)][k=kt*32+(l>>4)*8+j])
// and convert x_user/x_movie f32 -> bf16 tables (RNE; identical numerics to
// in-register conversion, half the gather bytes, cache-resident working set).
__global__ void prep(const float* __restrict__ W1, const float* __restrict__ W2,
                     const float* __restrict__ xu, const float* __restrict__ xm,
                     short* __restrict__ pW1, short* __restrict__ pW2,
                     short* __restrict__ xub, short* __restrict__ xmb,
                     int Nu, int Nm) {
  int tid = blockIdx.x * 256 + threadIdx.x;
  if (tid < 32768) {
    int j = tid & 7, l = (tid >> 3) & 63, frag = tid >> 9;
    int mt = frag >> 2, kt = frag & 3;
    int n = mt * 16 + (l & 15);
    int k = kt * 32 + ((l >> 4) * 8) + j;
    pW1[tid] = f2bf(W1[k * 256 + n]);
  } else if (tid < 98304) {
    int t2 = tid - 32768;
    int j = t2 & 7, l = (t2 >> 3) & 63, frag = t2 >> 9;
    int mt = frag >> 3, kt = frag & 7;
    int n = mt * 16 + (l & 15);
    int k = kt * 32 + ((l >> 4) * 8) + j;
    pW2[t2] = f2bf(W2[k * 256 + n]);
  } else {
    int c = tid - 98304;
    int tu = Nu * 8;
    int total = tu + Nm * 8;
    if (c < total) {
      const float* s; short* d;
      if (c < tu) { s = xu + (size_t)c * 8; d = xub + (size_t)c * 8; }
      else { int c2 = c - tu; s = xm + (size_t)c2 * 8; d = xmb + (size_t)c2 * 8; }
      v4f a = *(const v4f*)s, b = *(const v4f*)(s + 4);
      v4u o = { pk2(a[0], a[1]), pk2(a[2], a[3]), pk2(b[0], b[1]), pk2(b[2], b[3]) };
      *(v4u*)d = o;
    }
  }
}

#define LDX_S 136   // 128 + 8 pad shorts
#define LDH_S 264   // 256 + 8 pad shorts
#define LDP_S 20    // 16 slots + 4 pad floats
#define XBUF (64 * LDX_S)   // 8704 shorts / buffer
#define HBUF (64 * LDH_S)   // 16896 shorts / buffer
#define PBUF (64 * LDP_S)   // 1280 floats / buffer
#define SMEM_BYTES (2*XBUF*2 + 2*HBUF*2 + 2*PBUF*4)   // 112640

// v20 = v16's 3-waves/SIMD structure with B-waves split by EDGE-HALF, not
// row-half. Evidence chain:
//  - v19: arch-VGPR 108 + AGPR acc => total ~140-170/wave => 2-blocks/CU is
//    arithmetically closed (512-reg SIMD pool). Occupancy stayed 21.8%.
//  - v16: 12 waves (1A+2B/SIMD, cap 170) DID reach 33% occupancy, no spill --
//    but row-split B-waves duplicated every H read 2x (conflicts 2.75e7) and
//    the gain was cancelled.
//  - v20: 8 B-waves = 4 row-groups x 2 edge-halves. Each B-wave: 64 W2 rows x
//    32 edges x 8 kt = 64 MFMA, 16 H-reads. Block totals: H reads = v12
//    exactly (no duplication), MFMA = v12, conflicts should return to 1.65e7.
//    Cost: W2 L2-streaming doubles (~51 B/cyc/CU vs ~60 ceiling) -- the one
//    pipe with slack. The 3rd wave/SIMD now hides ds_read->MFMA latency
//    without an LDS tax.
// A-waves (w%3==0, wg=w/3): v12 verbatim. One barrier per phase, all waves.
__global__ __launch_bounds__(768, 3) void mlp_v20(
    const short* __restrict__ xub, const short* __restrict__ xmb,
    const void* __restrict__ eidx,
    const short* __restrict__ pW1, const short* __restrict__ pW2,
    const float* __restrict__ b1, const float* __restrict__ b2,
    const float* __restrict__ W3, const float* __restrict__ b3,
    float* __restrict__ out, int E)
{
  extern __shared__ __align__(16) char smem[];
  short* ldsX = (short*)smem;                       // [2][XBUF]
  short* ldsH = (short*)(smem + 2 * XBUF * 2);      // [2][HBUF]
  float* ldsP = (float*)(smem + 2 * XBUF * 2 + 2 * HBUF * 2); // [2][PBUF]

  const int t    = threadIdx.x;
  const int w    = t >> 6;        // 0..11
  const int lane = t & 63;
  const int quad = lane >> 4;
  const int lp   = lane & 15;
  const bool isA = ((w % 3) == 0);     // waves 0,3,6,9 -> 1 A per SIMD either mapping

  const unsigned* ew = (const unsigned*)eidx;
  unsigned oddw = (lane < 32) ? ew[2 * lane + 1] : 0u;
  const bool i64 = (__ballot(oddw != 0u) == 0ull);

  const int ntiles = (E + 63) >> 6;
  const int S   = (int)gridDim.x;
  const int bid = (int)blockIdx.x;
  const int Tb  = (ntiles - bid + S - 1) / S;
  const float bias3 = b3[0];

  if (isA) {
    // ===== producer: gather (bf16) + layer 1 (+ store on wg==0) =====
    const int wg = w / 3;               // 0..3
    const v8s* w1v = (const v8s*)pW1;
    v8s rW1[4][4];
#pragma unroll
    for (int mi = 0; mi < 4; ++mi)
#pragma unroll
      for (int kt = 0; kt < 4; ++kt)
        rW1[mi][kt] = w1v[(((wg * 4 + mi) * 4) + kt) * 64 + lane];
    v4f rb1[4];
#pragma unroll
    for (int mi = 0; mi < 4; ++mi)
      rb1[mi] = *(const v4f*)(b1 + wg * 64 + mi * 16 + quad * 4);

    const int ra = wg * 64 + lane;      // 4 threads/edge
    const int gi = ra >> 2, gq = ra & 3;

    auto loadIdx = [&](int tl, int& row, int& col) {
      int gE = tl * 64 + gi;
      if (gE >= E || gE < 0) gE = 0;
      if (i64) {
        const long long* p = (const long long*)eidx;
        row = (int)p[gE]; col = (int)p[(long long)E + gE];
      } else {
        const int* p = (const int*)eidx;
        row = p[gE]; col = p[E + gE];
      }
    };

    v4u u0, u1, m0, m1;
    auto issueUM = [&](int row, int col) {
      const v4u* pu = (const v4u*)(xub + (size_t)row * 64 + gq * 16);
      const v4u* pm = (const v4u*)(xmb + (size_t)col * 64 + gq * 16);
      u0 = pu[0]; u1 = pu[1]; m0 = pm[0]; m1 = pm[1];
    };

    int rowN, colN;
    loadIdx(bid, rowN, colN);
    issueUM(rowN, colN);
    loadIdx(bid + S, rowN, colN);

    for (int k = 0; k <= Tb + 2; ++k) {
      __syncthreads();
      const int pb = k & 1;
      const int tg = bid + k * S;

      // ---- commit prefetched bf16 features -> ldsX[pb]
      if (k < Tb) {
        short* px = &ldsX[pb * XBUF + gi * LDX_S + gq * 16];
        *(v4u*)(px)      = u0;  *(v4u*)(px + 8)  = u1;   // user  -> k 0..63
        *(v4u*)(px + 64) = m0;  *(v4u*)(px + 72) = m1;   // movie -> k 64..127
      }
      // ---- prefetch features(t_{k+1}), indices(t_{k+2})
      if (k + 1 < Tb) {
        issueUM(rowN, colN);
        loadIdx(tg + 2 * S, rowN, colN);
      }

      // ---- reduce + store tile t3 from ldsP[pb^1] (wave wg==0, lane = edge)
      const int t3 = tg - 3 * S;
      if (t3 >= 0 && wg == 0) {
        const v4f* pp = (const v4f*)&ldsP[(pb ^ 1) * PBUF + lane * LDP_S];
        float r = bias3;
#pragma unroll
        for (int c = 0; c < 4; ++c) {
          v4f p = pp[c];
          r += (p[0] + p[1]) + (p[2] + p[3]);
        }
        int o = t3 * 64 + lane;
        if (o < E) out[o] = r;
      }

      // ---- layer 1 of t1 : ldsX[pb^1] -> ldsH[pb^1]
      const int t1 = tg - S;
      if (t1 >= 0 && t1 < ntiles) {
        const short* xb = &ldsX[(pb ^ 1) * XBUF];
#pragma unroll 1
        for (int nh = 0; nh < 2; ++nh) {       // ni halves: acc live = 32 VGPR
          v4f acc[4][2];
#pragma unroll
          for (int mi = 0; mi < 4; ++mi) { acc[mi][0] = rb1[mi]; acc[mi][1] = rb1[mi]; }
          __builtin_amdgcn_s_setprio(1);
#pragma unroll
          for (int kt = 0; kt < 4; ++kt) {
            v8s bf0 = *(const v8s*)&xb[((nh * 2 + 0) * 16 + lp) * LDX_S + kt * 32 + quad * 8];
            v8s bf1 = *(const v8s*)&xb[((nh * 2 + 1) * 16 + lp) * LDX_S + kt * 32 + quad * 8];
#pragma unroll
            for (int mi = 0; mi < 4; ++mi) {
              acc[mi][0] = __builtin_amdgcn_mfma_f32_16x16x32_bf16(rW1[mi][kt], bf0, acc[mi][0], 0, 0, 0);
              acc[mi][1] = __builtin_amdgcn_mfma_f32_16x16x32_bf16(rW1[mi][kt], bf1, acc[mi][1], 0, 0, 0);
            }
          }
          __builtin_amdgcn_s_setprio(0);
#pragma unroll
          for (int mi = 0; mi < 4; ++mi) {
            int nh0 = wg * 64 + mi * 16 + quad * 4;
#pragma unroll
            for (int nj = 0; nj < 2; ++nj) {
              int e = (nh * 2 + nj) * 16 + lp;
              v4f v = acc[mi][nj];
              v2u pw; pw.x = pk2(fmaxf(v[0], 0.f), fmaxf(v[1], 0.f));
              pw.y = pk2(fmaxf(v[2], 0.f), fmaxf(v[3], 0.f));
              *(v2u*)&ldsH[(pb ^ 1) * HBUF + e * LDH_S + nh0] = pw;
            }
          }
        }
      }
    }
  } else {
    // ===== consumer: layer 2 (64 rows x 32 edges) + bias/ReLU + W3 fold =====
    const int bi = (w / 3) * 2 + (w % 3) - 1;   // 0..7
    const int rg = bi >> 1;                     // row-group: rows rg*64..rg*64+63
    const int eh = bi & 1;                      // edge-half: edges eh*32..eh*32+31
    const v8s* w2v = (const v8s*)pW2;
    v8s rW2[4][8];                      // 64 rows of W2 (streamed from L2 by compiler)
#pragma unroll
    for (int mi = 0; mi < 4; ++mi)
#pragma unroll
      for (int kt = 0; kt < 8; ++kt)
        rW2[mi][kt] = w2v[(((rg * 4 + mi) * 8) + kt) * 64 + lane];
    v4f rb2[4], rw3[4];
#pragma unroll
    for (int mi = 0; mi < 4; ++mi) {
      int nh0 = rg * 64 + mi * 16 + quad * 4;
      rb2[mi] = *(const v4f*)(b2 + nh0);
      rw3[mi] = *(const v4f*)(W3 + nh0);
    }

    for (int k = 0; k <= Tb + 2; ++k) {
      __syncthreads();
      const int pb = k & 1;
      const int tg = bid + k * S;
      const int t2 = tg - 2 * S;
      if (t2 >= 0 && t2 < ntiles) {
        const short* hbr = &ldsH[pb * HBUF];
        float* pPw = &ldsP[pb * PBUF];
        v4f acc2[4][2];
#pragma unroll
        for (int mi = 0; mi < 4; ++mi) { acc2[mi][0] = rb2[mi]; acc2[mi][1] = rb2[mi]; }
        __builtin_amdgcn_s_setprio(1);
#pragma unroll
        for (int kt = 0; kt < 8; ++kt) {
          v8s bf0 = *(const v8s*)&hbr[((eh * 2 + 0) * 16 + lp) * LDH_S + kt * 32 + quad * 8];
          v8s bf1 = *(const v8s*)&hbr[((eh * 2 + 1) * 16 + lp) * LDH_S + kt * 32 + quad * 8];
#pragma unroll
          for (int mi = 0; mi < 4; ++mi) {
            acc2[mi][0] = __builtin_amdgcn_mfma_f32_16x16x32_bf16(rW2[mi][kt], bf0, acc2[mi][0], 0, 0, 0);
            acc2[mi][1] = __builtin_amdgcn_mfma_f32_16x16x32_bf16(rW2[mi][kt], bf1, acc2[mi][1], 0, 0, 0);
          }
        }
        __builtin_amdgcn_s_setprio(0);
        float s0 = 0.f, s1 = 0.f;
#pragma unroll
        for (int mi = 0; mi < 4; ++mi) {
#pragma unroll
          for (int r = 0; r < 4; ++r) {
            s0 += fmaxf(acc2[mi][0][r], 0.f) * rw3[mi][r];
            s1 += fmaxf(acc2[mi][1][r], 0.f) * rw3[mi][r];
          }
        }
        int e0 = (eh * 2 + 0) * 16 + lp, e1 = (eh * 2 + 1) * 16 + lp;
        pPw[e0 * LDP_S + rg * 4 + quad] = s0;
        pPw[e1 * LDP_S + rg * 4 + quad] = s1;
      }
    }
  }
}

extern "C" void kernel_launch(void* const* d_in, const int* in_sizes, int n_in,
                              void* d_out, int out_size, void* d_ws, size_t ws_size,
                              hipStream_t stream) {
  const float* xu  = (const float*)d_in[0];
  const float* xm  = (const float*)d_in[1];
  const void*  ei  = d_in[2];
  const float* W1  = (const float*)d_in[3];
  const float* b1  = (const float*)d_in[4];
  const float* W2  = (const float*)d_in[5];
  const float* b2  = (const float*)d_in[6];
  const float* W3  = (const float*)d_in[7];
  const float* b3  = (const float*)d_in[8];
  float* out = (float*)d_out;

  const int E  = in_sizes[2] / 2;
  const int Nu = in_sizes[0] / 64;
  const int Nm = in_sizes[1] / 64;

  short* pW1 = (short*)d_ws;          // 64 KB
  short* pW2 = pW1 + 32768;           // 128 KB
  short* xub = (short*)((char*)d_ws + 196608);
  short* xmb = xub + (size_t)Nu * 64;

  const int cvt_blocks = ((Nu + Nm) * 8 + 255) / 256;
  hipLaunchKernelGGL(prep, dim3(384 + cvt_blocks), dim3(256), 0, stream,
                     W1, W2, xu, xm, pW1, pW2, xub, xmb, Nu, Nm);

  hipFuncSetAttribute((const void*)mlp_v20,
                      hipFuncAttributeMaxDynamicSharedMemorySize, SMEM_BYTES);

  const int ntiles = (E + 63) / 64;
  const int nblk = ntiles < 256 ? ntiles : 256;
  hipLaunchKernelGGL(mlp_v20, dim3(nblk), dim3(768), SMEM_BYTES, stream,
                     xub, xmb, ei, pW1, pW2, b1, b2, W3, b3, out, E);
}